// Round 7
// baseline (1781.906 us; speedup 1.0000x reference)
//
#include <hip/hip_runtime.h>
#include <cstddef>

#define Bv 4
#define Nv 24
#define NTv 16
#define Tv 64
#define NP 25
#define NEGF (-1e30f)
#define GRID 192

// ---------------- workspace layout (floats) ----------------
#define BETAA_OFF 0         // [B][25][25][16 sym][24 head]            960000
#define BETAU_OFF 960000    // [B][25][25][64 sym]                     160000
#define RNT_OFF   1120000   // [B][2 d][24 h][16 A][16 sL][16 sR]      786432
#define T0_OFF    1906432   // [B][24 h][24 p][16 sL][16 A]            589824
#define T1_OFF    2496256   // [B][24 h][24 p][16 sR][16 A]            589824
#define T0L_OFF   3086080   // [B][24 h][16 sR][16 A]                  24576
#define T1R_OFF   3110656   // [B][24 h][16 sL][16 A]                  24576
#define D0_OFF    3135232   // [B][24 l][16 A]                         1536
#define D1_OFF    3136768   // [B][24 l][16 A]                         1536
#define MA_OFF    3138304   // [B][25][25][24 h] max_sym betaA         60000
#define MU_OFF    3198304   // [B][25][25]       max_sym betau(NT)     2500
#define BAR_OFF   3200804   // 2 ints: barrier cnt + gen
#define WS_NEED   3200808

__device__ __forceinline__ float shflmax16(float v) {
  v = fmaxf(v, __shfl_xor(v, 8, 16));
  v = fmaxf(v, __shfl_xor(v, 4, 16));
  v = fmaxf(v, __shfl_xor(v, 2, 16));
  v = fmaxf(v, __shfl_xor(v, 1, 16));
  return v;
}

// sense-reversing grid barrier: one arriving lane per block, agent-scope
__device__ __forceinline__ void grid_barrier(int* cnt, int* gen) {
  __syncthreads();
  if (threadIdx.x == 0) {
    __threadfence();  // release prior writes device-wide
    int g = __hip_atomic_load(gen, __ATOMIC_RELAXED, __HIP_MEMORY_SCOPE_AGENT);
    int prev = __hip_atomic_fetch_add(cnt, 1, __ATOMIC_ACQ_REL, __HIP_MEMORY_SCOPE_AGENT);
    if (prev == GRID - 1) {
      __hip_atomic_store(cnt, 0, __ATOMIC_RELAXED, __HIP_MEMORY_SCOPE_AGENT);
      __hip_atomic_store(gen, g + 1, __ATOMIC_RELEASE, __HIP_MEMORY_SCOPE_AGENT);
    } else {
      while (__hip_atomic_load(gen, __ATOMIC_ACQUIRE, __HIP_MEMORY_SCOPE_AGENT) == g)
        __builtin_amdgcn_s_sleep(2);
    }
    __threadfence();  // acquire
  }
  __syncthreads();
}

__device__ __forceinline__ void edge_dot2(float v0, float v1, float v2, float v3,
                                          float t0, float t1, float t2, float t3,
                                          float& sh, float& S) {
  float mx = fmaxf(fmaxf(v0, v1), fmaxf(v2, v3));
  mx = fmaxf(mx, __shfl_xor(mx, 1, 64));
  mx = fmaxf(mx, __shfl_xor(mx, 2, 64));
  float dot = __expf(v0 - mx) * t0 + __expf(v1 - mx) * t1 +
              __expf(v2 - mx) * t2 + __expf(v3 - mx) * t3;
  dot += __shfl_xor(dot, 1, 64);
  dot += __shfl_xor(dot, 2, 64);
  sh = mx;
  S = dot;
}

// ================= single cooperative kernel =================
__global__ __launch_bounds__(768, 1) void coop_kernel(
    const float* __restrict__ unary, const float* __restrict__ rule,
    const float* __restrict__ root, float* __restrict__ out, float* __restrict__ ws) {
  float* betaA = ws + BETAA_OFF;
  float* betau = ws + BETAU_OFF;
  float* RNT = ws + RNT_OFF;
  float* T0 = ws + T0_OFF;
  float* T1 = ws + T1_OFF;
  float* T0L = ws + T0L_OFF;
  float* T1R = ws + T1R_OFF;
  float* D0 = ws + D0_OFF;
  float* D1 = ws + D1_OFF;
  float* MA = ws + MA_OFF;
  float* MU = ws + MU_OFF;
  int* bcnt = (int*)(ws + BAR_OFF);
  int* bgen = bcnt + 1;

  __shared__ float smem[29184];  // prep: 3*9728 ; width: 15088
  const int tid = threadIdx.x, bid = blockIdx.x;

  // ---------------- prep: 1536 units (b,A,h); 3 sub-units of 256 thr ----------------
  {
    const int sub = tid >> 8, tpl = tid & 255;
    float* lb = smem + sub * 9728;
    float* er0 = lb;          // 64*65
    float* er1 = lb + 4160;   // 64*65
    float* E = lb + 8320;     // 24*48
    float* red = lb + 9472;   // 256
    for (int base = 0; base < 1536; base += 3 * GRID) {
      const int u = base + bid * 3 + sub;
      const bool valid = u < 1536;
      const int ue = valid ? u : 0;
      const int b = ue / 384, remu = ue % 384, A = remu / 24, h = remu % 24;
      __syncthreads();
      for (int i = tpl; i < 1152; i += 256)
        E[i] = __expf(unary[(size_t)(b * Nv + i / 48) * Tv + 16 + i % 48]);
      const float* rb = rule + (size_t)((b * NTv + A) * Nv + h) * 8192;
#pragma unroll
      for (int i = 0; i < 8; ++i) {
        int lin = i * 1024 + tpl * 4;  // sL*128 + sR*2 + d
        float4 v = *(const float4*)(rb + lin);
        int sL = lin >> 7, r2 = (lin & 127) >> 1;
        er0[sL * 65 + r2] = __expf(v.x);
        er1[sL * 65 + r2] = __expf(v.y);
        er0[sL * 65 + r2 + 1] = __expf(v.z);
        er1[sL * 65 + r2 + 1] = __expf(v.w);
      }
      __syncthreads();
      if (valid) {  // RNT, A-major
        float* dst0 = RNT + (((size_t)(b * 2 + 0) * Nv + h) * NTv + A) * 256;
        float* dst1 = RNT + (((size_t)(b * 2 + 1) * Nv + h) * NTv + A) * 256;
        dst0[tpl] = er0[(tpl >> 4) * 65 + (tpl & 15)];
        dst1[tpl] = er1[(tpl >> 4) * 65 + (tpl & 15)];
      }
      for (int o = tpl; o < 384; o += 256) {  // T0 / T1
        int p = o >> 4, sL = o & 15;
        const float* Ep = E + p * 48;
        const float* r0 = er0 + sL * 65 + 16;
        float a0 = 0.f, a1 = 0.f;
#pragma unroll 8
        for (int j = 0; j < 48; ++j) a0 += Ep[j] * r0[j];
#pragma unroll 8
        for (int i = 0; i < 48; ++i) a1 += Ep[i] * er1[(16 + i) * 65 + sL];
        if (valid) {
          T0[(((size_t)(b * Nv + h) * Nv + p) * NTv + sL) * NTv + A] = a0;
          T1[(((size_t)(b * Nv + h) * Nv + p) * NTv + sL) * NTv + A] = a1;
        }
      }
      if (tpl < 16) {  // T0L
        float acc = 0.f;
        for (int i = 0; i < 48; ++i) acc += er0[(16 + i) * 65 + tpl];
        if (valid) T0L[((size_t)(b * Nv + h) * NTv + tpl) * NTv + A] = acc;
      } else if (tpl < 32) {  // T1R
        int sL = tpl - 16;
        float acc = 0.f;
        for (int j = 0; j < 48; ++j) acc += er1[sL * 65 + 16 + j];
        if (valid) T1R[((size_t)(b * Nv + h) * NTv + sL) * NTv + A] = acc;
      }
      float acc0 = 0.f, acc1 = 0.f;  // D0 / D1
      const int hp = (h + 1 < 24) ? h + 1 : 0, hm = (h >= 1) ? h - 1 : 0;
      for (int e = tpl; e < 2304; e += 256) {
        int i = e / 48, j = e % 48;
        acc0 += E[hp * 48 + j] * er0[(16 + i) * 65 + 16 + j];
        acc1 += E[hm * 48 + i] * er1[(16 + i) * 65 + 16 + j];
      }
      red[tpl] = acc0;
      __syncthreads();
      if (tpl < 64) {
        float s = red[tpl] + red[tpl + 64] + red[tpl + 128] + red[tpl + 192];
#pragma unroll
        for (int off = 32; off; off >>= 1) s += __shfl_xor(s, off, 64);
        if (tpl == 0 && valid && h <= 22) D0[((size_t)b * Nv + h) * NTv + A] = s;
      }
      __syncthreads();
      red[tpl] = acc1;
      __syncthreads();
      if (tpl < 64) {
        float s = red[tpl] + red[tpl + 64] + red[tpl + 128] + red[tpl + 192];
#pragma unroll
        for (int off = 32; off; off >>= 1) s += __shfl_xor(s, off, 64);
        if (tpl == 0 && valid && h >= 1) D1[((size_t)b * Nv + (h - 1)) * NTv + A] = s;
      }
    }
  }
  grid_barrier(bcnt, bgen);

  // ---------------- width DP ----------------
  float* U0 = smem;            // 24*256
  float* U1 = smem + 6144;     // 24*256
  float* sG0 = smem + 12288;   // 24
  float* sG1 = smem + 12312;   // 24
  float* cLs = smem + 12336;   // 16*25
  float* ecRs = smem + 12736;  // 16*25
  float* eLs = smem + 13136;   // 16
  float* eeRs = smem + 13152;  // 16
  float* pM = smem + 13168;    // 2*24*16
  float* pS = smem + 13936;    // 2*24*16
  float* sTmp = smem + 14704;  // 16*24

  for (int W = 2; W <= Nv; ++W) {
    const int ntask = (NP - W) * 4;
    for (int task = bid; task < ntask; task += GRID) {
      const int l = task >> 2, b = task & 3;
      const int r = l + W;

      // ---- edge staging ----
      if (W >= 3) {
        if (tid < 384) {
          int s = tid / 24, j = tid % 24, jj = j - l;
          float v = betaA[((size_t)(b * NP + l) * NP + (r - 1)) * 384 + s * 24 + j];
          if (jj >= 0 && jj < 24) cLs[s * 25 + jj] = v;
        } else {
          int t2 = tid - 384;
          int s = t2 / 24, j = t2 % 24, jj = j - l;
          float v = betaA[((size_t)(b * NP + (l + 1)) * NP + r) * 384 + s * 24 + j];
          if (jj >= 0 && jj < 24) ecRs[s * 25 + jj] = v;
        }
        if (tid < 16) eLs[tid] = betau[((size_t)(b * NP + l) * NP + (r - 1)) * Tv + tid];
        else if (tid >= 32 && tid < 48)
          eeRs[tid - 32] = betau[((size_t)(b * NP + (l + 1)) * NP + r) * Tv + (tid - 32)];
      }

      // ---- Phase A: fixed-shift, full preload ----
      const int g = tid >> 5, k = tid & 31;
      const int cnt = W - 3;
      float U0r[8], U1r[8];
#pragma unroll
      for (int j = 0; j < 8; ++j) { U0r[j] = 0.f; U1r[j] = 0.f; }
      float G0 = NEGF, G1 = NEGF;

      if (g < W) {
        const int h = l + g;
        float pMAlm = NEGF, pMUlm = NEGF, pMAmr = NEGF, pMUmr = NEGF;
        float sh0 = NEGF, sh1 = NEGF;
        if (k < cnt) {
          int m = l + 2 + k;
          pMAlm = MA[((size_t)(b * NP + l) * NP + m) * 24 + h];
          pMUlm = MU[(size_t)(b * NP + l) * NP + m];
          pMAmr = MA[((size_t)(b * NP + m) * NP + r) * 24 + h];
          pMUmr = MU[(size_t)(b * NP + m) * NP + r];
          if (k >= g - 1) sh0 = pMAlm + pMUmr;
          if (k <= g - 2) sh1 = pMUlm + pMAmr;
        }
        float m0 = sh0, m1 = sh1;
#pragma unroll
        for (int off = 16; off; off >>= 1) {
          m0 = fmaxf(m0, __shfl_xor(m0, off, 32));
          m1 = fmaxf(m1, __shfl_xor(m1, off, 32));
        }
        G0 = m0;
        G1 = m1;
        float pw0 = (sh0 == NEGF) ? 0.f : __expf(sh0 - G0);
        float pw1 = (sh1 == NEGF) ? 0.f : __expf(sh1 - G1);

        if (cnt > 0) {
          size_t cbase, cstr, bbase, bstr;
          if (k < 16) {
            cbase = ((size_t)(b * NP + l) * NP) * 384 + (size_t)k * 24 + h;
            cstr = 384;
            bbase = ((size_t)(b * NP + l) * NP) * 64 + k;
            bstr = 64;
          } else {
            cbase = (size_t)(b * NP) * NP * 384 + (size_t)r * 384 + (size_t)(k - 16) * 24 + h;
            cstr = (size_t)NP * 384;
            bbase = (size_t)(b * NP) * NP * 64 + (size_t)r * 64 + (k - 16);
            bstr = (size_t)NP * 64;
          }
          float cvA[21], bvA[21];
#pragma unroll
          for (int i = 0; i < 21; ++i) {
            if (i < cnt) {
              cvA[i] = betaA[cbase + (size_t)(l + 2 + i) * cstr];
              bvA[i] = betau[bbase + (size_t)(l + 2 + i) * bstr];
            }
          }
#pragma unroll
          for (int i = 0; i < 21; ++i) {
            if (i < cnt) {
              float bMAlm = __shfl(pMAlm, i, 32), bMUlm = __shfl(pMUlm, i, 32);
              float bMAmr = __shfl(pMAmr, i, 32), bMUmr = __shfl(pMUmr, i, 32);
              float bw0 = __shfl(pw0, i, 32), bw1 = __shfl(pw1, i, 32);
              float subc = (k < 16) ? bMAlm : bMAmr;
              float subb = (k < 16) ? bMUlm : bMUmr;
              float eC = __expf(fminf(cvA[i] - subc, 0.f));
              float eB = __expf(fminf(bvA[i] - subb, 0.f));
              float s0 = __shfl(eB, 16 + (k & 15), 32) * bw0;
              float s1 = __shfl(eC, 16 + (k & 15), 32) * bw1;
#pragma unroll
              for (int j = 0; j < 8; ++j) {
                int sL = (k >> 4) + 2 * j;
                U0r[j] = fmaf(__shfl(eC, sL, 32), s0, U0r[j]);
                U1r[j] = fmaf(__shfl(eB, sL, 32), s1, U1r[j]);
              }
            }
          }
        }
#pragma unroll
        for (int j = 0; j < 8; ++j) {
          U0[g * 256 + k + 32 * j] = U0r[j];
          U1[g * 256 + k + 32 * j] = U1r[j];
        }
        if (k == 0) { sG0[g] = G0; sG1[g] = G1; }
      }
      __syncthreads();

      // ---- Phase B ----
      {
        const int w = tid >> 6, lane = tid & 63;
        const int A = lane >> 2, q = lane & 3;
        for (int p = w; p < 2 * W; p += 12) {
          const int hh = p >> 1, d = p & 1;
          const int h = l + hh;
          bool hasE2 = false, hasE3 = false;
          const float* Tb2 = nullptr;
          const float* Tb3 = nullptr;
          if (W >= 3) {
            if (d == 0) {
              if (hh < W - 1) { hasE2 = true; Tb2 = T0 + (((size_t)(b * Nv + h) * Nv + (r - 1)) * NTv + 4 * q) * NTv + A; }
              if (hh == 0)    { hasE3 = true; Tb3 = T0L + ((size_t)(b * Nv + l) * NTv + 4 * q) * NTv + A; }
            } else {
              if (hh >= 1)    { hasE2 = true; Tb2 = T1 + (((size_t)(b * Nv + h) * Nv + l) * NTv + 4 * q) * NTv + A; }
              if (hh == W - 1){ hasE3 = true; Tb3 = T1R + ((size_t)(b * Nv + (r - 1)) * NTv + 4 * q) * NTv + A; }
            }
          }
          float t20 = 0.f, t21 = 0.f, t22 = 0.f, t23 = 0.f;
          float t30 = 0.f, t31 = 0.f, t32 = 0.f, t33 = 0.f;
          if (hasE2) { t20 = Tb2[0]; t21 = Tb2[16]; t22 = Tb2[32]; t23 = Tb2[48]; }
          if (hasE3) { t30 = Tb3[0]; t31 = Tb3[16]; t32 = Tb3[32]; t33 = Tb3[48]; }

          const float* Urow = (d ? U1 : U0) + hh * 256 + 4 * q;
          const float* Rb = RNT + (((size_t)(b * 2 + d) * Nv + h) * NTv + A) * 256 + 4 * q;
          float acc = 0.f;
#pragma unroll
          for (int sL = 0; sL < 16; ++sL) {
            float4 u = *(const float4*)(Urow + sL * 16);
            float4 rv = *(const float4*)(Rb + sL * 16);
            acc += u.x * rv.x + u.y * rv.y + u.z * rv.z + u.w * rv.w;
          }
          acc += __shfl_xor(acc, 1, 64);
          acc += __shfl_xor(acc, 2, 64);
          float Mi = d ? sG1[hh] : sG0[hh];
          float sh2 = NEGF, S2 = 0.f, sh3 = NEGF, S3 = 0.f;
          if (W >= 3) {
            if (hasE2) {
              if (d == 0)
                edge_dot2(cLs[(4 * q + 0) * 25 + hh], cLs[(4 * q + 1) * 25 + hh],
                          cLs[(4 * q + 2) * 25 + hh], cLs[(4 * q + 3) * 25 + hh],
                          t20, t21, t22, t23, sh2, S2);
              else
                edge_dot2(ecRs[(4 * q + 0) * 25 + hh], ecRs[(4 * q + 1) * 25 + hh],
                          ecRs[(4 * q + 2) * 25 + hh], ecRs[(4 * q + 3) * 25 + hh],
                          t20, t21, t22, t23, sh2, S2);
            }
            if (hasE3) {
              if (d == 0)
                edge_dot2(eeRs[4 * q + 0], eeRs[4 * q + 1], eeRs[4 * q + 2], eeRs[4 * q + 3],
                          t30, t31, t32, t33, sh3, S3);
              else
                edge_dot2(eLs[4 * q + 0], eLs[4 * q + 1], eLs[4 * q + 2], eLs[4 * q + 3],
                          t30, t31, t32, t33, sh3, S3);
            }
          } else {
            if (d == 0 && hh == 0) { sh2 = 0.f; S2 = D0[((size_t)b * Nv + l) * NTv + A]; }
            if (d == 1 && hh == 1) { sh2 = 0.f; S2 = D1[((size_t)b * Nv + l) * NTv + A]; }
          }
          float Mf = fmaxf(Mi, fmaxf(sh2, sh3));
          float Sf = acc * __expf(Mi - Mf) + S2 * __expf(sh2 - Mf) + S3 * __expf(sh3 - Mf);
          if (q == 0) {
            pM[(d * 24 + hh) * 16 + A] = Mf;
            pS[(d * 24 + hh) * 16 + A] = Sf;
          }
        }
      }
      __syncthreads();
      // combine, write betaA + MA; betau + MU; fused final at root span
      if (tid < 384) {
        int A2 = tid & 15, hh = tid >> 4;
        if (hh < W) {
          float M0 = pM[(0 * 24 + hh) * 16 + A2], S0 = pS[(0 * 24 + hh) * 16 + A2];
          float M1 = pM[(1 * 24 + hh) * 16 + A2], S1 = pS[(1 * 24 + hh) * 16 + A2];
          float nm = fmaxf(M0, M1);
          float s = S0 * __expf(M0 - nm) + S1 * __expf(M1 - nm);
          float val = nm + __logf(s);
          betaA[((size_t)(b * NP + l) * NP + r) * 384 + A2 * 24 + (l + hh)] = val;
          sTmp[A2 * 24 + hh] = val + unary[(size_t)(b * Nv + (l + hh)) * Tv + A2];
          float mv = shflmax16(val);
          if (A2 == 0) MA[((size_t)(b * NP + l) * NP + r) * 24 + (l + hh)] = mv;
        }
      }
      __syncthreads();
      if (tid < 16) {
        float mx = NEGF;
        for (int x = 0; x < W; ++x) mx = fmaxf(mx, sTmp[tid * 24 + x]);
        float s = 0.f;
        for (int x = 0; x < W; ++x) s += __expf(sTmp[tid * 24 + x] - mx);
        float v = mx + __logf(s);
        betau[((size_t)(b * NP + l) * NP + r) * Tv + tid] = v;
        float mv = shflmax16(v);
        if (tid == 0) MU[(size_t)(b * NP + l) * NP + r] = mv;
        if (W == Nv && l == 0) {  // fused final
          float qv = v + root[b * NTv + tid];
          float qmx = shflmax16(qv);
          float e = __expf(qv - qmx);
          e += __shfl_xor(e, 8, 16);
          e += __shfl_xor(e, 4, 16);
          e += __shfl_xor(e, 2, 16);
          e += __shfl_xor(e, 1, 16);
          if (tid == 0) out[b] = qmx + __logf(e);
        }
      }
      __syncthreads();
    }
    if (W < Nv) grid_barrier(bcnt, bgen);
  }
}

// ================= fallback path (small ws): R1-style, known-correct =================
__global__ void init_betau_kernel(const float* __restrict__ unary, float* __restrict__ betau) {
  int t = blockIdx.x * blockDim.x + threadIdx.x;
  if (t >= Bv * Nv * 48) return;
  int i = t % 48, kk = (t / 48) % Nv, b = t / (48 * Nv);
  betau[((size_t)(b * NP + kk) * NP + (kk + 1)) * Tv + 16 + i] =
      unary[(size_t)(b * Nv + kk) * Tv + 16 + i];
}

__global__ __launch_bounds__(768) void width_kernel_fb(
    const float* __restrict__ unary, const float* __restrict__ rule,
    float* __restrict__ betaA, float* __restrict__ betau, int W) {
  const int l = blockIdx.x, b = blockIdx.y;
  const int r = l + W;
  const int tid = threadIdx.x;
  const int sub = tid & 1;
  const int pid = tid >> 1;
  const int A = pid & 15;
  const int hh = pid >> 4;
  const int h = l + hh;
  const bool act = (hh < W);
  const int sA = tid & 15, sH = tid >> 4;

  __shared__ float sER0[48], sEL1[48];
  __shared__ float sCL0[16 * 24], sCR1[16 * 24];
  __shared__ float sMaxL0[24], sMaxR1[24];
  __shared__ float sShR0, sShL1;
  __shared__ float sTmp[16 * 24];

  float runM = NEGF, runS = 0.f;
  for (int m = l + 1; m < r; ++m) {
    const int wl = m - l, wr = r - m;
    if (tid < 64) {
      const int n = (wr == 1) ? 48 : 16, s0 = (wr == 1) ? 16 : 0;
      float v = (tid < n) ? betau[(size_t)((b * NP + m) * NP + r) * Tv + s0 + tid] : NEGF;
      float mx = v;
#pragma unroll
      for (int off = 32; off; off >>= 1) mx = fmaxf(mx, __shfl_xor(mx, off, 64));
      if (tid == 0) sShR0 = mx;
      if (tid < n) sER0[tid] = v - mx;
    } else if (tid < 128) {
      const int j = tid - 64;
      const int n = (wl == 1) ? 48 : 16, s0 = (wl == 1) ? 16 : 0;
      float v = (j < n) ? betau[(size_t)((b * NP + l) * NP + m) * Tv + s0 + j] : NEGF;
      float mx = v;
#pragma unroll
      for (int off = 32; off; off >>= 1) mx = fmaxf(mx, __shfl_xor(mx, off, 64));
      if (j == 0) sShL1 = mx;
      if (j < n) sEL1[j] = v - mx;
    }
    if (tid < 384) {
      if (wl > 1 && sH < wl) {
        float v = betaA[(size_t)((b * NP + l) * NP + m) * 384 + sA * Nv + (l + sH)];
        float mx = v;
#pragma unroll
        for (int off = 8; off; off >>= 1) mx = fmaxf(mx, __shfl_xor(mx, off, 16));
        if (sA == 0) sMaxL0[sH] = mx;
        sCL0[sA * Nv + sH] = v - mx;
      }
      if (wr > 1 && sH >= wl && sH < W) {
        float v = betaA[(size_t)((b * NP + m) * NP + r) * 384 + sA * Nv + (l + sH)];
        float mx = v;
#pragma unroll
        for (int off = 8; off; off >>= 1) mx = fmaxf(mx, __shfl_xor(mx, off, 16));
        if (sA == 0) sMaxR1[sH] = mx;
        sCR1[sA * Nv + sH] = v - mx;
      }
    }
    __syncthreads();
    if (act) {
      if (hh < wl && (wl > 1 || hh == 0)) {
        const int nL = (wl == 1) ? 48 : 16, sL0 = (wl == 1) ? 16 : 0;
        const int nR = (wr == 1) ? 48 : 16, sR0 = (wr == 1) ? 16 : 0;
        const float shift = ((wl == 1) ? 0.f : sMaxL0[hh]) + sShR0;
        float part = 0.f;
        const float* rb = rule + (size_t)(((b * NTv + A) * Nv + h) * Tv) * Tv * 2;
        for (int i = sub; i < nL; i += 2) {
          const float cl = (wl == 1) ? 0.f : sCL0[i * Nv + hh];
          const float* rp = rb + (size_t)(sL0 + i) * Tv * 2 + sR0 * 2;
#pragma unroll 8
          for (int j = 0; j < nR; ++j) part += __expf(cl + sER0[j] + rp[j * 2]);
        }
        float nm = fmaxf(runM, shift);
        runS = runS * __expf(runM - nm) + part * __expf(shift - nm);
        runM = nm;
      }
      if (hh >= wl && (wr > 1 || hh == W - 1)) {
        const int nL = (wl == 1) ? 48 : 16, sL0 = (wl == 1) ? 16 : 0;
        const int nR = (wr == 1) ? 48 : 16, sR0 = (wr == 1) ? 16 : 0;
        const float shift = sShL1 + ((wr == 1) ? 0.f : sMaxR1[hh]);
        float part = 0.f;
        const float* rb = rule + (size_t)(((b * NTv + A) * Nv + h) * Tv) * Tv * 2 + 1;
        for (int i = sub; i < nL; i += 2) {
          const float el = sEL1[i];
          const float* rp = rb + (size_t)(sL0 + i) * Tv * 2 + sR0 * 2;
#pragma unroll 8
          for (int j = 0; j < nR; ++j) {
            const float cr = (wr == 1) ? 0.f : sCR1[j * Nv + hh];
            part += __expf(el + cr + rp[j * 2]);
          }
        }
        float nm = fmaxf(runM, shift);
        runS = runS * __expf(runM - nm) + part * __expf(shift - nm);
        runM = nm;
      }
    }
    __syncthreads();
  }
  if (act) {
    float om = __shfl_xor(runM, 1, 64);
    float os = __shfl_xor(runS, 1, 64);
    float nm = fmaxf(runM, om);
    float s = runS * __expf(runM - nm) + os * __expf(om - nm);
    if (sub == 0) {
      float val = nm + __logf(s);
      betaA[(size_t)((b * NP + l) * NP + r) * 384 + A * Nv + h] = val;
      sTmp[A * Nv + hh] = val + unary[(b * Nv + h) * Tv + A];
    }
  }
  __syncthreads();
  if (tid < 16) {
    float mx = NEGF;
    for (int x = 0; x < W; ++x) mx = fmaxf(mx, sTmp[tid * Nv + x]);
    float s = 0.f;
    for (int x = 0; x < W; ++x) s += __expf(sTmp[tid * Nv + x] - mx);
    betau[(size_t)((b * NP + l) * NP + r) * Tv + tid] = mx + __logf(s);
  }
}

__global__ void final_kernel(const float* __restrict__ betau, const float* __restrict__ root,
                             float* __restrict__ out) {
  int b = threadIdx.x;
  if (b < Bv) {
    float vals[NTv];
    float mx = NEGF;
#pragma unroll
    for (int A = 0; A < NTv; ++A) {
      float v = betau[(size_t)((b * NP + 0) * NP + Nv) * Tv + A] + root[b * NTv + A];
      vals[A] = v;
      mx = fmaxf(mx, v);
    }
    float s = 0.f;
#pragma unroll
    for (int A = 0; A < NTv; ++A) s += __expf(vals[A] - mx);
    out[b] = mx + __logf(s);
  }
}

extern "C" void kernel_launch(void* const* d_in, const int* in_sizes, int n_in,
                              void* d_out, int out_size, void* d_ws, size_t ws_size,
                              hipStream_t stream) {
  (void)in_sizes; (void)n_in; (void)out_size;
  const float* unary = (const float*)d_in[0];
  const float* rule  = (const float*)d_in[1];
  const float* root  = (const float*)d_in[2];
  float* out = (float*)d_out;
  float* ws = (float*)d_ws;
  const bool fast = ws_size >= (size_t)WS_NEED * sizeof(float);

  if (fast) {
    hipMemsetAsync((void*)(ws + BAR_OFF), 0, 2 * sizeof(int), stream);
    void* args[] = {(void*)&unary, (void*)&rule, (void*)&root, (void*)&out, (void*)&ws};
    hipLaunchCooperativeKernel((void*)coop_kernel, dim3(GRID), dim3(768), args, 0, stream);
  } else {
    float* betaA = ws + BETAA_OFF;
    float* betau = ws + BETAU_OFF;
    init_betau_kernel<<<(Bv * Nv * 48 + 255) / 256, 256, 0, stream>>>(unary, betau);
    for (int W = 2; W <= Nv; ++W) {
      dim3 grid(Nv - W + 1, Bv);
      width_kernel_fb<<<grid, 768, 0, stream>>>(unary, rule, betaA, betau, W);
    }
    final_kernel<<<1, 64, 0, stream>>>(betau, root, out);
  }
}

// Round 8
// 660.612 us; speedup vs baseline: 2.6974x; 2.6974x over previous
//
#include <hip/hip_runtime.h>
#include <cstddef>

#define Bv 4
#define Nv 24
#define NTv 16
#define Tv 64
#define NP 25
#define NEGF (-1e30f)

// ---------------- workspace layout (floats) ----------------
#define BETAA_OFF 0         // [B][25][25][16 sym][24 head]            960000
#define BETAU_OFF 960000    // [B][25][25][64 sym]                     160000
#define RNT_OFF   1120000   // [B][2 d][24 h][16 A][16 sL][16 sR]      786432
#define T0_OFF    1906432   // [B][24 h][24 p][16 sL][16 A]            589824
#define T1_OFF    2496256   // [B][24 h][24 p][16 sR][16 A]            589824
#define T0L_OFF   3086080   // [B][24 h][16 sR][16 A]                  24576
#define T1R_OFF   3110656   // [B][24 h][16 sL][16 A]                  24576
#define D0_OFF    3135232   // [B][24 l][16 A]                         1536
#define D1_OFF    3136768   // [B][24 l][16 A]                         1536
#define MA_OFF    3138304   // [B][25][25][24 h] max_sym betaA         60000
#define MU_OFF    3198304   // [B][25][25]       max_sym betau(NT)     2500
#define WS_NEED   3200804

__device__ __forceinline__ float shflmax16(float v) {
  v = fmaxf(v, __shfl_xor(v, 8, 16));
  v = fmaxf(v, __shfl_xor(v, 4, 16));
  v = fmaxf(v, __shfl_xor(v, 2, 16));
  v = fmaxf(v, __shfl_xor(v, 1, 16));
  return v;
}

// ---- fused prep: block per (b,A,h); coalesced 32KB rule read; all precontractions ----
__global__ __launch_bounds__(256) void prep_kernel2(
    const float* __restrict__ rule, const float* __restrict__ unary,
    float* __restrict__ RNT, float* __restrict__ T0, float* __restrict__ T1,
    float* __restrict__ T0L, float* __restrict__ T1R,
    float* __restrict__ D0, float* __restrict__ D1) {
  const int h = blockIdx.x, A = blockIdx.y, b = blockIdx.z;
  const int t = threadIdx.x;  // 256
  __shared__ float er0[64 * 65];
  __shared__ float er1[64 * 65];
  __shared__ float E[24 * 48];
  __shared__ float red[256];

  for (int i = t; i < 1152; i += 256)
    E[i] = __expf(unary[(size_t)(b * Nv + i / 48) * Tv + 16 + i % 48]);
  const float* rb = rule + (size_t)((b * NTv + A) * Nv + h) * 8192;
#pragma unroll
  for (int i = 0; i < 8; ++i) {
    int lin = i * 1024 + t * 4;  // sL*128 + sR*2 + d
    float4 v = *(const float4*)(rb + lin);
    int sL = lin >> 7, rem = (lin & 127) >> 1;
    er0[sL * 65 + rem] = __expf(v.x);
    er1[sL * 65 + rem] = __expf(v.y);
    er0[sL * 65 + rem + 1] = __expf(v.z);
    er1[sL * 65 + rem + 1] = __expf(v.w);
  }
  __syncthreads();
  {  // RNT, A-major
    float* dst0 = RNT + (((size_t)(b * 2 + 0) * Nv + h) * NTv + A) * 256;
    float* dst1 = RNT + (((size_t)(b * 2 + 1) * Nv + h) * NTv + A) * 256;
    dst0[t] = er0[(t >> 4) * 65 + (t & 15)];
    dst1[t] = er1[(t >> 4) * 65 + (t & 15)];
  }
  for (int o = t; o < 384; o += 256) {  // T0 / T1
    int p = o >> 4, sL = o & 15;
    const float* Ep = E + p * 48;
    const float* r0 = er0 + sL * 65 + 16;
    float a0 = 0.f, a1 = 0.f;
#pragma unroll 8
    for (int j = 0; j < 48; ++j) a0 += Ep[j] * r0[j];
#pragma unroll 8
    for (int i = 0; i < 48; ++i) a1 += Ep[i] * er1[(16 + i) * 65 + sL];
    T0[(((size_t)(b * Nv + h) * Nv + p) * NTv + sL) * NTv + A] = a0;
    T1[(((size_t)(b * Nv + h) * Nv + p) * NTv + sL) * NTv + A] = a1;
  }
  if (t < 16) {  // T0L
    float acc = 0.f;
    for (int i = 0; i < 48; ++i) acc += er0[(16 + i) * 65 + t];
    T0L[((size_t)(b * Nv + h) * NTv + t) * NTv + A] = acc;
  } else if (t < 32) {  // T1R
    int sL = t - 16;
    float acc = 0.f;
    for (int j = 0; j < 48; ++j) acc += er1[sL * 65 + 16 + j];
    T1R[((size_t)(b * Nv + h) * NTv + sL) * NTv + A] = acc;
  }
  // D0 / D1
  float acc0 = 0.f, acc1 = 0.f;
  const int hp = (h + 1 < 24) ? h + 1 : 0, hm = (h >= 1) ? h - 1 : 0;
  for (int e = t; e < 2304; e += 256) {
    int i = e / 48, j = e % 48;
    acc0 += E[hp * 48 + j] * er0[(16 + i) * 65 + 16 + j];
    acc1 += E[hm * 48 + i] * er1[(16 + i) * 65 + 16 + j];
  }
  red[t] = acc0;
  __syncthreads();
  if (t < 64) {
    float s = red[t] + red[t + 64] + red[t + 128] + red[t + 192];
#pragma unroll
    for (int off = 32; off; off >>= 1) s += __shfl_xor(s, off, 64);
    if (t == 0 && h <= 22) D0[((size_t)b * Nv + h) * NTv + A] = s;
  }
  __syncthreads();
  red[t] = acc1;
  __syncthreads();
  if (t < 64) {
    float s = red[t] + red[t + 64] + red[t + 128] + red[t + 192];
#pragma unroll
    for (int off = 32; off; off >>= 1) s += __shfl_xor(s, off, 64);
    if (t == 0 && h >= 1) D1[((size_t)b * Nv + (h - 1)) * NTv + A] = s;
  }
}

__device__ __forceinline__ void edge_dot2(float v0, float v1, float v2, float v3,
                                          float t0, float t1, float t2, float t3,
                                          float& sh, float& S) {
  float mx = fmaxf(fmaxf(v0, v1), fmaxf(v2, v3));
  mx = fmaxf(mx, __shfl_xor(mx, 1, 64));
  mx = fmaxf(mx, __shfl_xor(mx, 2, 64));
  float dot = __expf(v0 - mx) * t0 + __expf(v1 - mx) * t1 +
              __expf(v2 - mx) * t2 + __expf(v3 - mx) * t3;
  dot += __shfl_xor(dot, 1, 64);
  dot += __shfl_xor(dot, 2, 64);
  sh = mx;
  S = dot;
}

// ---- pair kernel: standalone width-W1 spans + width-W2 parents that locally
//      recompute their two W1 children (no cross-block deps inside a launch) ----
__global__ __launch_bounds__(768) void pair_kernel(
    const float* __restrict__ unary, float* __restrict__ betaA, float* __restrict__ betau,
    const float* __restrict__ RNT, const float* __restrict__ T0, const float* __restrict__ T1,
    const float* __restrict__ T0L, const float* __restrict__ T1R,
    const float* __restrict__ D0, const float* __restrict__ D1,
    float* __restrict__ MA, float* __restrict__ MU,
    const float* __restrict__ root, float* __restrict__ out, int W1, int W2) {
  __shared__ float U0[24 * 256], U1[24 * 256];
  __shared__ float sG0[24], sG1[24];
  __shared__ float cE_L[16 * 25], cE_R[16 * 25];  // staged edges (global source)
  __shared__ float eE_L[16], eE_R[16];
  __shared__ float cP_L[16 * 25], cP_R[16 * 25];  // parent's locally-computed children
  __shared__ float eP_L[16], eP_R[16];
  __shared__ float pM[2 * 24 * 16], pS[2 * 24 * 16];
  __shared__ float sTmp[16 * 24];

  const int tid = threadIdx.x;
  const int nStand = 4 * (NP - W1);
  const bool isPar = (W2 > 0) && ((int)blockIdx.x >= nStand);
  const int id = isPar ? ((int)blockIdx.x - nStand) : (int)blockIdx.x;
  const int b = id & 3, l0 = id >> 2;
  const int nsp = isPar ? 3 : 1;

  for (int si = 0; si < nsp; ++si) {
    int sl, sw, hhOff = 0;
    bool wg = true, efl = false;  // write-global; edges-from-LDS
    float* rA = nullptr;
    float* rU = nullptr;
    if (!isPar) { sl = l0; sw = W1; }
    else if (si == 0) { sl = l0; sw = W2 - 1; wg = false; rA = cP_L; rU = eP_L; hhOff = 0; }
    else if (si == 1) { sl = l0 + 1; sw = W2 - 1; wg = false; rA = cP_R; rU = eP_R; hhOff = 1; }
    else { sl = l0; sw = W2; efl = true; }
    const int sr = sl + sw;

    // ---- edge staging (children of width sw-1; from global unless parent span) ----
    if (sw >= 3 && !efl) {
      if (tid < 384) {
        int s = tid / 24, j = tid % 24, jj = j - sl;
        float v = betaA[((size_t)(b * NP + sl) * NP + (sr - 1)) * 384 + s * 24 + j];
        if (jj >= 0 && jj < 24) cE_L[s * 25 + jj] = v;
      } else {
        int t2 = tid - 384;
        int s = t2 / 24, j = t2 % 24, jj = j - sl;
        float v = betaA[((size_t)(b * NP + (sl + 1)) * NP + sr) * 384 + s * 24 + j];
        if (jj >= 0 && jj < 24) cE_R[s * 25 + jj] = v;
      }
      if (tid < 16) eE_L[tid] = betau[((size_t)(b * NP + sl) * NP + (sr - 1)) * Tv + tid];
      else if (tid >= 32 && tid < 48)
        eE_R[tid - 32] = betau[((size_t)(b * NP + (sl + 1)) * NP + sr) * Tv + (tid - 32)];
    }
    const float* cLp = efl ? cP_L : cE_L;
    const float* cRp = efl ? cP_R : cE_R;
    const float* eLp = efl ? eP_L : eE_L;
    const float* eRp = efl ? eP_R : eE_R;

    // ---- Phase A: fixed-shift, full preload (interior splits all width <= sw-2: global) ----
    const int g = tid >> 5, k = tid & 31;
    const int cnt = sw - 3;
    float U0r[8], U1r[8];
#pragma unroll
    for (int j = 0; j < 8; ++j) { U0r[j] = 0.f; U1r[j] = 0.f; }
    float G0 = NEGF, G1 = NEGF;

    if (g < sw) {
      const int h = sl + g;
      float pMAlm = NEGF, pMUlm = NEGF, pMAmr = NEGF, pMUmr = NEGF;
      float sh0 = NEGF, sh1 = NEGF;
      if (k < cnt) {
        int m = sl + 2 + k;
        pMAlm = MA[((size_t)(b * NP + sl) * NP + m) * 24 + h];
        pMUlm = MU[(size_t)(b * NP + sl) * NP + m];
        pMAmr = MA[((size_t)(b * NP + m) * NP + sr) * 24 + h];
        pMUmr = MU[(size_t)(b * NP + m) * NP + sr];
        if (k >= g - 1) sh0 = pMAlm + pMUmr;
        if (k <= g - 2) sh1 = pMUlm + pMAmr;
      }
      float m0 = sh0, m1 = sh1;
#pragma unroll
      for (int off = 16; off; off >>= 1) {
        m0 = fmaxf(m0, __shfl_xor(m0, off, 32));
        m1 = fmaxf(m1, __shfl_xor(m1, off, 32));
      }
      G0 = m0;
      G1 = m1;
      float pw0 = (sh0 == NEGF) ? 0.f : __expf(sh0 - G0);
      float pw1 = (sh1 == NEGF) ? 0.f : __expf(sh1 - G1);

      if (cnt > 0) {
        size_t cbase, cstr, bbase, bstr;
        if (k < 16) {
          cbase = ((size_t)(b * NP + sl) * NP) * 384 + (size_t)k * 24 + h;
          cstr = 384;
          bbase = ((size_t)(b * NP + sl) * NP) * 64 + k;
          bstr = 64;
        } else {
          cbase = (size_t)(b * NP) * NP * 384 + (size_t)sr * 384 + (size_t)(k - 16) * 24 + h;
          cstr = (size_t)NP * 384;
          bbase = (size_t)(b * NP) * NP * 64 + (size_t)sr * 64 + (k - 16);
          bstr = (size_t)NP * 64;
        }
        float cvA[21], bvA[21];
#pragma unroll
        for (int i = 0; i < 21; ++i) {
          if (i < cnt) {
            cvA[i] = betaA[cbase + (size_t)(sl + 2 + i) * cstr];
            bvA[i] = betau[bbase + (size_t)(sl + 2 + i) * bstr];
          }
        }
#pragma unroll
        for (int i = 0; i < 21; ++i) {
          if (i < cnt) {
            float bMAlm = __shfl(pMAlm, i, 32), bMUlm = __shfl(pMUlm, i, 32);
            float bMAmr = __shfl(pMAmr, i, 32), bMUmr = __shfl(pMUmr, i, 32);
            float bw0 = __shfl(pw0, i, 32), bw1 = __shfl(pw1, i, 32);
            float subc = (k < 16) ? bMAlm : bMAmr;
            float subb = (k < 16) ? bMUlm : bMUmr;
            float eC = __expf(fminf(cvA[i] - subc, 0.f));
            float eB = __expf(fminf(bvA[i] - subb, 0.f));
            float s0 = __shfl(eB, 16 + (k & 15), 32) * bw0;
            float s1 = __shfl(eC, 16 + (k & 15), 32) * bw1;
#pragma unroll
            for (int j = 0; j < 8; ++j) {
              int sLn = (k >> 4) + 2 * j;
              U0r[j] = fmaf(__shfl(eC, sLn, 32), s0, U0r[j]);
              U1r[j] = fmaf(__shfl(eB, sLn, 32), s1, U1r[j]);
            }
          }
        }
      }
#pragma unroll
      for (int j = 0; j < 8; ++j) {
        U0[g * 256 + k + 32 * j] = U0r[j];
        U1[g * 256 + k + 32 * j] = U1r[j];
      }
      if (k == 0) { sG0[g] = G0; sG1[g] = G1; }
    }
    __syncthreads();

    // ---- Phase B ----
    {
      const int w = tid >> 6, lane = tid & 63;
      const int A = lane >> 2, q = lane & 3;
      for (int p = w; p < 2 * sw; p += 12) {
        const int hh = p >> 1, d = p & 1;
        const int h = sl + hh;
        bool hasE2 = false, hasE3 = false;
        const float* Tb2 = nullptr;
        const float* Tb3 = nullptr;
        if (sw >= 3) {
          if (d == 0) {
            if (hh < sw - 1) { hasE2 = true; Tb2 = T0 + (((size_t)(b * Nv + h) * Nv + (sr - 1)) * NTv + 4 * q) * NTv + A; }
            if (hh == 0)     { hasE3 = true; Tb3 = T0L + ((size_t)(b * Nv + sl) * NTv + 4 * q) * NTv + A; }
          } else {
            if (hh >= 1)     { hasE2 = true; Tb2 = T1 + (((size_t)(b * Nv + h) * Nv + sl) * NTv + 4 * q) * NTv + A; }
            if (hh == sw - 1){ hasE3 = true; Tb3 = T1R + ((size_t)(b * Nv + (sr - 1)) * NTv + 4 * q) * NTv + A; }
          }
        }
        float t20 = 0.f, t21 = 0.f, t22 = 0.f, t23 = 0.f;
        float t30 = 0.f, t31 = 0.f, t32 = 0.f, t33 = 0.f;
        if (hasE2) { t20 = Tb2[0]; t21 = Tb2[16]; t22 = Tb2[32]; t23 = Tb2[48]; }
        if (hasE3) { t30 = Tb3[0]; t31 = Tb3[16]; t32 = Tb3[32]; t33 = Tb3[48]; }

        const float* Urow = (d ? U1 : U0) + hh * 256 + 4 * q;
        const float* Rb = RNT + (((size_t)(b * 2 + d) * Nv + h) * NTv + A) * 256 + 4 * q;
        float acc = 0.f;
#pragma unroll
        for (int sL = 0; sL < 16; ++sL) {
          float4 u = *(const float4*)(Urow + sL * 16);
          float4 rv = *(const float4*)(Rb + sL * 16);
          acc += u.x * rv.x + u.y * rv.y + u.z * rv.z + u.w * rv.w;
        }
        acc += __shfl_xor(acc, 1, 64);
        acc += __shfl_xor(acc, 2, 64);
        float Mi = d ? sG1[hh] : sG0[hh];
        float sh2 = NEGF, S2 = 0.f, sh3 = NEGF, S3 = 0.f;
        if (sw >= 3) {
          if (hasE2) {
            if (d == 0)
              edge_dot2(cLp[(4 * q + 0) * 25 + hh], cLp[(4 * q + 1) * 25 + hh],
                        cLp[(4 * q + 2) * 25 + hh], cLp[(4 * q + 3) * 25 + hh],
                        t20, t21, t22, t23, sh2, S2);
            else
              edge_dot2(cRp[(4 * q + 0) * 25 + hh], cRp[(4 * q + 1) * 25 + hh],
                        cRp[(4 * q + 2) * 25 + hh], cRp[(4 * q + 3) * 25 + hh],
                        t20, t21, t22, t23, sh2, S2);
          }
          if (hasE3) {
            if (d == 0)
              edge_dot2(eRp[4 * q + 0], eRp[4 * q + 1], eRp[4 * q + 2], eRp[4 * q + 3],
                        t30, t31, t32, t33, sh3, S3);
            else
              edge_dot2(eLp[4 * q + 0], eLp[4 * q + 1], eLp[4 * q + 2], eLp[4 * q + 3],
                        t30, t31, t32, t33, sh3, S3);
          }
        } else {
          if (d == 0 && hh == 0) { sh2 = 0.f; S2 = D0[((size_t)b * Nv + sl) * NTv + A]; }
          if (d == 1 && hh == 1) { sh2 = 0.f; S2 = D1[((size_t)b * Nv + sl) * NTv + A]; }
        }
        float Mf = fmaxf(Mi, fmaxf(sh2, sh3));
        float Sf = acc * __expf(Mi - Mf) + S2 * __expf(sh2 - Mf) + S3 * __expf(sh3 - Mf);
        if (q == 0) {
          pM[(d * 24 + hh) * 16 + A] = Mf;
          pS[(d * 24 + hh) * 16 + A] = Sf;
        }
      }
    }
    __syncthreads();
    // ---- epilogue: combine dirs; write to global (standalone/parent) or LDS (child) ----
    if (tid < 384) {
      int A2 = tid & 15, hh = tid >> 4;
      if (hh < sw) {
        float M0 = pM[(0 * 24 + hh) * 16 + A2], S0 = pS[(0 * 24 + hh) * 16 + A2];
        float M1 = pM[(1 * 24 + hh) * 16 + A2], S1 = pS[(1 * 24 + hh) * 16 + A2];
        float nm = fmaxf(M0, M1);
        float s = S0 * __expf(M0 - nm) + S1 * __expf(M1 - nm);
        float val = nm + __logf(s);
        if (wg) {
          betaA[((size_t)(b * NP + sl) * NP + sr) * 384 + A2 * 24 + (sl + hh)] = val;
          float mv = shflmax16(val);
          if (A2 == 0) MA[((size_t)(b * NP + sl) * NP + sr) * 24 + (sl + hh)] = mv;
        } else {
          rA[A2 * 25 + hhOff + hh] = val;
        }
        sTmp[A2 * 24 + hh] = val + unary[(size_t)(b * Nv + (sl + hh)) * Tv + A2];
      }
    }
    __syncthreads();
    if (tid < 16) {
      float mx = NEGF;
      for (int x = 0; x < sw; ++x) mx = fmaxf(mx, sTmp[tid * 24 + x]);
      float s = 0.f;
      for (int x = 0; x < sw; ++x) s += __expf(sTmp[tid * 24 + x] - mx);
      float v = mx + __logf(s);
      if (wg) {
        betau[((size_t)(b * NP + sl) * NP + sr) * Tv + tid] = v;
        float mv = shflmax16(v);
        if (tid == 0) MU[(size_t)(b * NP + sl) * NP + sr] = mv;
        if (sw == Nv && sl == 0) {  // fused final output
          float qv = v + root[b * NTv + tid];
          float qmx = shflmax16(qv);
          float e = __expf(qv - qmx);
          e += __shfl_xor(e, 8, 16);
          e += __shfl_xor(e, 4, 16);
          e += __shfl_xor(e, 2, 16);
          e += __shfl_xor(e, 1, 16);
          if (tid == 0) out[b] = qmx + __logf(e);
        }
      } else {
        rU[tid] = v;
      }
    }
    __syncthreads();
  }
}

// ================= fallback path (small ws): R1-style, known-correct =================
__global__ void init_betau_kernel(const float* __restrict__ unary, float* __restrict__ betau) {
  int t = blockIdx.x * blockDim.x + threadIdx.x;
  if (t >= Bv * Nv * 48) return;
  int i = t % 48, kk = (t / 48) % Nv, b = t / (48 * Nv);
  betau[((size_t)(b * NP + kk) * NP + (kk + 1)) * Tv + 16 + i] =
      unary[(size_t)(b * Nv + kk) * Tv + 16 + i];
}

__global__ __launch_bounds__(768) void width_kernel_fb(
    const float* __restrict__ unary, const float* __restrict__ rule,
    float* __restrict__ betaA, float* __restrict__ betau, int W) {
  const int l = blockIdx.x, b = blockIdx.y;
  const int r = l + W;
  const int tid = threadIdx.x;
  const int sub = tid & 1;
  const int pid = tid >> 1;
  const int A = pid & 15;
  const int hh = pid >> 4;
  const int h = l + hh;
  const bool act = (hh < W);
  const int sA = tid & 15, sH = tid >> 4;

  __shared__ float sER0[48], sEL1[48];
  __shared__ float sCL0[16 * 24], sCR1[16 * 24];
  __shared__ float sMaxL0[24], sMaxR1[24];
  __shared__ float sShR0, sShL1;
  __shared__ float sTmp[16 * 24];

  float runM = NEGF, runS = 0.f;
  for (int m = l + 1; m < r; ++m) {
    const int wl = m - l, wr = r - m;
    if (tid < 64) {
      const int n = (wr == 1) ? 48 : 16, s0 = (wr == 1) ? 16 : 0;
      float v = (tid < n) ? betau[(size_t)((b * NP + m) * NP + r) * Tv + s0 + tid] : NEGF;
      float mx = v;
#pragma unroll
      for (int off = 32; off; off >>= 1) mx = fmaxf(mx, __shfl_xor(mx, off, 64));
      if (tid == 0) sShR0 = mx;
      if (tid < n) sER0[tid] = v - mx;
    } else if (tid < 128) {
      const int j = tid - 64;
      const int n = (wl == 1) ? 48 : 16, s0 = (wl == 1) ? 16 : 0;
      float v = (j < n) ? betau[(size_t)((b * NP + l) * NP + m) * Tv + s0 + j] : NEGF;
      float mx = v;
#pragma unroll
      for (int off = 32; off; off >>= 1) mx = fmaxf(mx, __shfl_xor(mx, off, 64));
      if (j == 0) sShL1 = mx;
      if (j < n) sEL1[j] = v - mx;
    }
    if (tid < 384) {
      if (wl > 1 && sH < wl) {
        float v = betaA[(size_t)((b * NP + l) * NP + m) * 384 + sA * Nv + (l + sH)];
        float mx = v;
#pragma unroll
        for (int off = 8; off; off >>= 1) mx = fmaxf(mx, __shfl_xor(mx, off, 16));
        if (sA == 0) sMaxL0[sH] = mx;
        sCL0[sA * Nv + sH] = v - mx;
      }
      if (wr > 1 && sH >= wl && sH < W) {
        float v = betaA[(size_t)((b * NP + m) * NP + r) * 384 + sA * Nv + (l + sH)];
        float mx = v;
#pragma unroll
        for (int off = 8; off; off >>= 1) mx = fmaxf(mx, __shfl_xor(mx, off, 16));
        if (sA == 0) sMaxR1[sH] = mx;
        sCR1[sA * Nv + sH] = v - mx;
      }
    }
    __syncthreads();
    if (act) {
      if (hh < wl && (wl > 1 || hh == 0)) {
        const int nL = (wl == 1) ? 48 : 16, sL0 = (wl == 1) ? 16 : 0;
        const int nR = (wr == 1) ? 48 : 16, sR0 = (wr == 1) ? 16 : 0;
        const float shift = ((wl == 1) ? 0.f : sMaxL0[hh]) + sShR0;
        float part = 0.f;
        const float* rb = rule + (size_t)(((b * NTv + A) * Nv + h) * Tv) * Tv * 2;
        for (int i = sub; i < nL; i += 2) {
          const float cl = (wl == 1) ? 0.f : sCL0[i * Nv + hh];
          const float* rp = rb + (size_t)(sL0 + i) * Tv * 2 + sR0 * 2;
#pragma unroll 8
          for (int j = 0; j < nR; ++j) part += __expf(cl + sER0[j] + rp[j * 2]);
        }
        float nm = fmaxf(runM, shift);
        runS = runS * __expf(runM - nm) + part * __expf(shift - nm);
        runM = nm;
      }
      if (hh >= wl && (wr > 1 || hh == W - 1)) {
        const int nL = (wl == 1) ? 48 : 16, sL0 = (wl == 1) ? 16 : 0;
        const int nR = (wr == 1) ? 48 : 16, sR0 = (wr == 1) ? 16 : 0;
        const float shift = sShL1 + ((wr == 1) ? 0.f : sMaxR1[hh]);
        float part = 0.f;
        const float* rb = rule + (size_t)(((b * NTv + A) * Nv + h) * Tv) * Tv * 2 + 1;
        for (int i = sub; i < nL; i += 2) {
          const float el = sEL1[i];
          const float* rp = rb + (size_t)(sL0 + i) * Tv * 2 + sR0 * 2;
#pragma unroll 8
          for (int j = 0; j < nR; ++j) {
            const float cr = (wr == 1) ? 0.f : sCR1[j * Nv + hh];
            part += __expf(el + cr + rp[j * 2]);
          }
        }
        float nm = fmaxf(runM, shift);
        runS = runS * __expf(runM - nm) + part * __expf(shift - nm);
        runM = nm;
      }
    }
    __syncthreads();
  }
  if (act) {
    float om = __shfl_xor(runM, 1, 64);
    float os = __shfl_xor(runS, 1, 64);
    float nm = fmaxf(runM, om);
    float s = runS * __expf(runM - nm) + os * __expf(om - nm);
    if (sub == 0) {
      float val = nm + __logf(s);
      betaA[(size_t)((b * NP + l) * NP + r) * 384 + A * Nv + h] = val;
      sTmp[A * Nv + hh] = val + unary[(b * Nv + h) * Tv + A];
    }
  }
  __syncthreads();
  if (tid < 16) {
    float mx = NEGF;
    for (int x = 0; x < W; ++x) mx = fmaxf(mx, sTmp[tid * Nv + x]);
    float s = 0.f;
    for (int x = 0; x < W; ++x) s += __expf(sTmp[tid * Nv + x] - mx);
    betau[(size_t)((b * NP + l) * NP + r) * Tv + tid] = mx + __logf(s);
  }
}

__global__ void final_kernel(const float* __restrict__ betau, const float* __restrict__ root,
                             float* __restrict__ out) {
  int b = threadIdx.x;
  if (b < Bv) {
    float vals[NTv];
    float mx = NEGF;
#pragma unroll
    for (int A = 0; A < NTv; ++A) {
      float v = betau[(size_t)((b * NP + 0) * NP + Nv) * Tv + A] + root[b * NTv + A];
      vals[A] = v;
      mx = fmaxf(mx, v);
    }
    float s = 0.f;
#pragma unroll
    for (int A = 0; A < NTv; ++A) s += __expf(vals[A] - mx);
    out[b] = mx + __logf(s);
  }
}

extern "C" void kernel_launch(void* const* d_in, const int* in_sizes, int n_in,
                              void* d_out, int out_size, void* d_ws, size_t ws_size,
                              hipStream_t stream) {
  (void)in_sizes; (void)n_in; (void)out_size;
  const float* unary = (const float*)d_in[0];
  const float* rule  = (const float*)d_in[1];
  const float* root  = (const float*)d_in[2];
  float* out = (float*)d_out;
  float* ws = (float*)d_ws;
  float* betaA = ws + BETAA_OFF;
  float* betau = ws + BETAU_OFF;
  const bool fast = ws_size >= (size_t)WS_NEED * sizeof(float);

  if (fast) {
    float* RNT = ws + RNT_OFF;
    float* T0  = ws + T0_OFF;
    float* T1  = ws + T1_OFF;
    float* T0L = ws + T0L_OFF;
    float* T1R = ws + T1R_OFF;
    float* D0  = ws + D0_OFF;
    float* D1  = ws + D1_OFF;
    float* MAp = ws + MA_OFF;
    float* MUp = ws + MU_OFF;
    prep_kernel2<<<dim3(24, 16, 4), 256, 0, stream>>>(rule, unary, RNT, T0, T1, T0L, T1R, D0, D1);
    // pairs (2,3),(4,5),...,(22,23), then standalone 24 (with fused final output)
    for (int W1 = 2; W1 <= Nv; W1 += 2) {
      const int W2 = (W1 < Nv) ? W1 + 1 : 0;
      const int nblk = 4 * (NP - W1) + (W2 ? 4 * (NP - W2) : 0);
      pair_kernel<<<nblk, 768, 0, stream>>>(unary, betaA, betau, RNT, T0, T1, T0L, T1R,
                                            D0, D1, MAp, MUp, root, out, W1, W2);
    }
  } else {
    init_betau_kernel<<<(Bv * Nv * 48 + 255) / 256, 256, 0, stream>>>(unary, betau);
    for (int W = 2; W <= Nv; ++W) {
      dim3 grid(Nv - W + 1, Bv);
      width_kernel_fb<<<grid, 768, 0, stream>>>(unary, rule, betaA, betau, W);
    }
    final_kernel<<<1, 64, 0, stream>>>(betau, root, out);
  }
}